// Round 1
// baseline (99.328 us; speedup 1.0000x reference)
//
#include <hip/hip_runtime.h>
#include <math.h>

typedef __attribute__((ext_vector_type(8))) _Float16 f16x8;
typedef __attribute__((ext_vector_type(4))) float f32x4;

#define NPIX 4096
#define C_DIM 128
// 1/sqrt(128) * log2(e): scores arrive in log2-space -> exp2 (v_exp_f32 native)
#define SCALE2 0.12752064638518208f

#if __has_builtin(__builtin_amdgcn_exp2f)
#define EXP2(x) __builtin_amdgcn_exp2f(x)
#else
#define EXP2(x) exp2f(x)
#endif

// Fully fused, workspace-free kernel.
// Key change vs prior version: the fp16 Y panel (workspace + conv_y kernel +
// global_load_lds staging) is gone. The MFMA A-fragment needs 8 channel-
// contiguous values per lane for one key; we load those directly from fp32 y
// as scalar dword loads (16 n16-lanes -> coalesced 64B segments), convert with
// the same RTE (_Float16) cast conv_y used, and keep the Y tile entirely in
// registers, software-pipelined one 128-key tile deep. Numerics are
// bit-identical to the previous two-kernel version.
__global__ __launch_bounds__(512, 2) void uv_fused(const float* __restrict__ x,
                                                   const float* __restrict__ y,
                                                   float* __restrict__ out)
{
    __shared__ float red[8][64][3];   // cross-wave reduce scratch (6 KB)

    const int t = threadIdx.x, w = t >> 6, l = t & 63;
    const int n16 = l & 15, quad = l >> 4;
    const int wg  = blockIdx.x;
    const int xcd = wg & 7;
    const int b   = xcd >> 1;                      // 2 XCDs per batch: y batch (2MB) L2-resident
    const int qt  = ((xcd & 1) << 5) | (wg >> 3);  // 0..63
    const int q0  = qt * 64;

    // ---- one-time: X B-fragments fp16 (SCALE2 folded: scores in log2-space). 64 VGPRs. ----
    f16x8 bx[4][4];                                // [cc][qg]
    {
        const float* xq = x + (size_t)b * C_DIM * NPIX + q0 + n16;
        #pragma unroll
        for (int cc = 0; cc < 4; ++cc)
            #pragma unroll
            for (int qg = 0; qg < 4; ++qg) {
                f16x8 hh;
                #pragma unroll
                for (int j = 0; j < 8; ++j)
                    hh[j] = (_Float16)(xq[(size_t)(cc * 32 + quad * 8 + j) * NPIX + qg * 16] * SCALE2);
                bx[cc][qg] = hh;
            }
    }

    // per-lane Y base: A-frag lane (n16,quad) needs Y[c = cc*32+quad*8+j][key = kt*128+w*16+n16]
    const float* yq = y + ((size_t)b * C_DIM + quad * 8) * NPIX + w * 16 + n16;

    // D rows: tile-local key = w*16 + quad*4 + r
    float gxv[4];
    #pragma unroll
    for (int r = 0; r < 4; ++r) gxv[r] = (float)((w & 3) * 16 + quad * 4 + r) + 0.5f;
    const float gyw = (float)(w >> 2) + 0.5f;      // gy = 2*kt + gyw
    float den[4] = {0.f, 0.f, 0.f, 0.f}, nu[4] = {0.f, 0.f, 0.f, 0.f}, nv[4] = {0.f, 0.f, 0.f, 0.f};

    // double-buffered fp32 Y tile slices, fully-unrolled constant indices -> registers
    float fA[4][8], fB[4][8];

#define LOADT(BUF, KT) do {                                                     \
    const unsigned kof_ = (unsigned)(KT) * 128u;                                \
    _Pragma("unroll")                                                           \
    for (int cc_ = 0; cc_ < 4; ++cc_) {                                         \
        _Pragma("unroll")                                                       \
        for (int j_ = 0; j_ < 8; ++j_)                                          \
            BUF[cc_][j_] = yq[(unsigned)((cc_ * 32 + j_) * NPIX) + kof_];       \
    } } while (0)

#define BODY(KT, CUR) do {                                                      \
    f32x4 acc_[4];                                                              \
    _Pragma("unroll")                                                           \
    for (int qg_ = 0; qg_ < 4; ++qg_) acc_[qg_] = (f32x4){0.f, 0.f, 0.f, 0.f};  \
    _Pragma("unroll")                                                           \
    for (int cc_ = 0; cc_ < 4; ++cc_) {                                         \
        f16x8 A_;                                                               \
        _Pragma("unroll")                                                       \
        for (int j_ = 0; j_ < 8; ++j_) A_[j_] = (_Float16)CUR[cc_][j_];         \
        _Pragma("unroll")                                                       \
        for (int qg_ = 0; qg_ < 4; ++qg_)                                       \
            acc_[qg_] = __builtin_amdgcn_mfma_f32_16x16x32_f16(A_, bx[cc_][qg_], acc_[qg_], 0, 0, 0); \
    }                                                                           \
    const float gy_ = 2.0f * (float)(KT) + gyw;                                 \
    _Pragma("unroll")                                                           \
    for (int qg_ = 0; qg_ < 4; ++qg_) {                                         \
        float ps_ = 0.f, pc_ = 0.f;                                             \
        _Pragma("unroll")                                                       \
        for (int r_ = 0; r_ < 4; ++r_) {                                        \
            const float p_ = EXP2(acc_[qg_][r_]);                               \
            ps_ += p_;                                                          \
            pc_ += p_ * gxv[r_];                                                \
        }                                                                       \
        den[qg_] += ps_;                                                        \
        nu[qg_]  += pc_;                                                        \
        nv[qg_]  += gy_ * ps_;                                                  \
    } } while (0)

    // pipeline: issue tile kt+1's 32 loads before computing tile kt -> each
    // tile's loads get a full compute body (~500 cyc) of latency cover; the
    // compiler emits the counted vmcnt waits for this loop-carried pattern.
    LOADT(fA, 0);
    #pragma unroll 1
    for (int kt2 = 0; kt2 < 16; ++kt2) {
        const int kte = 2 * kt2;
        LOADT(fB, kte + 1);
        BODY(kte, fA);
        if (kt2 < 15) LOADT(fA, kte + 2);
        BODY(kte + 1, fB);
    }

#undef LOADT
#undef BODY

    // ---- reduce across quads (keys within wave), then across 8 waves via LDS ----
    #pragma unroll
    for (int qg = 0; qg < 4; ++qg) {
        #pragma unroll
        for (int mk = 16; mk <= 32; mk <<= 1) {
            den[qg] += __shfl_xor(den[qg], mk);
            nu[qg]  += __shfl_xor(nu[qg],  mk);
            nv[qg]  += __shfl_xor(nv[qg],  mk);
        }
    }
    if (quad == 0) {
        #pragma unroll
        for (int qg = 0; qg < 4; ++qg) {
            red[w][qg * 16 + n16][0] = den[qg];
            red[w][qg * 16 + n16][1] = nu[qg];
            red[w][qg * 16 + n16][2] = nv[qg];
        }
    }
    __syncthreads();
    if (t < 64) {
        float d = 0.f, u = 0.f, v = 0.f;
        #pragma unroll
        for (int ww = 0; ww < 8; ++ww) {
            d += red[ww][t][0];
            u += red[ww][t][1];
            v += red[ww][t][2];
        }
        const float inv = 1.0f / d;
        *(float2*)(out + ((size_t)b * NPIX + q0 + t) * 2) =
            make_float2(u * inv * 0.03125f - 1.0f, v * inv * 0.03125f - 1.0f);
    }
}

extern "C" void kernel_launch(void* const* d_in, const int* in_sizes, int n_in,
                              void* d_out, int out_size, void* d_ws, size_t ws_size,
                              hipStream_t stream) {
    (void)in_sizes; (void)n_in; (void)out_size; (void)d_ws; (void)ws_size;
    hipLaunchKernelGGL(uv_fused, dim3(256), dim3(512), 0, stream,
                       (const float*)d_in[0], (const float*)d_in[1], (float*)d_out);
}